// Round 4
// baseline (186.371 us; speedup 1.0000x reference)
//
#include <hip/hip_runtime.h>
#include <hip/hip_cooperative_groups.h>
#include <math.h>

namespace cg = cooperative_groups;

// ---------------------------------------------------------------------------
// RootCauseAttention: per-node scores -> edge segment-sum -> global softmax
//
// Structure (round 4):
//  K1 node_scores: s_src, t_dst(=s_dst+b_edge), self(=s_node+b_node); 16
//     lanes/node, float4 loads.
//  K2 edge_bin: LDS histograms. Grid (B=64 chunks) x (R=4 ranges of 16384),
//     1024 thr/block, 64 KB LDS. dst row loaded int4; src loaded SCALAR and
//     ONLY under the range predicate (round-3 loaded src unconditionally =
//     38 MB wasted). Histogram written to partials[b] with float4 stores.
//     (Global fp32 atomics measured at ~18 G/s memory-side RMW regardless of
//     scope — rounds 1-2 — hence the atomic-free design.)
//  K3 finalize (cooperative, 256x256): acc = self + sum_b partials, global
//     max via grid.sync, exp, global sum via grid.sync, normalize, write out.
//     Values live in registers across the syncs; no acc round-trip, no
//     global atomics. Fallback to 3 plain kernels if coop unsupported.
//
// Workspace (floats): s_src[N] | t_dst[N] | self[N] | acc[N] | gmax | gsum |
//                     red[512] | partials[B*N]
// ---------------------------------------------------------------------------

#define RANGE_BITS 14
#define RANGE_SIZE (1 << RANGE_BITS)   // 16384 nodes/range, 64 KB LDS
#define NCHUNKS 64
#define COOP_BLOCKS 256
#define COOP_THREADS 256
#define MAXITEMS 4

__device__ __forceinline__ void atomicMaxFloat(float* addr, float val) {
    if (val >= 0.0f) atomicMax((int*)addr, __float_as_int(val));
    else             atomicMin((unsigned int*)addr, __float_as_uint(val));
}

// ---------------- K1: node scores (16 lanes/node, float4) ------------------
__global__ __launch_bounds__(256) void node_scores_kernel(
    const float* __restrict__ h,
    const float* __restrict__ W_edge,   // [2H]
    const float* __restrict__ b_edge,   // [1]
    const float* __restrict__ W_node,   // [H]
    const float* __restrict__ b_node,   // [1]
    float* __restrict__ s_src,
    float* __restrict__ t_dst,
    float* __restrict__ self_sc,
    float* __restrict__ acc,            // pre-init to self (fallback paths)
    float* __restrict__ gmax,
    float* __restrict__ gsum,
    int N, int H)
{
    if (blockIdx.x == 0 && threadIdx.x == 0) { *gmax = -INFINITY; *gsum = 0.0f; }

    const int lane16 = threadIdx.x & 15;
    const int n = (blockIdx.x * blockDim.x + threadIdx.x) >> 4;
    if (n >= N) return;

    const float4* __restrict__ h4  = (const float4*)(h + (size_t)n * H);
    const float4* __restrict__ ws4 = (const float4*)(W_edge);
    const float4* __restrict__ wd4 = (const float4*)(W_edge + H);
    const float4* __restrict__ wn4 = (const float4*)(W_node);
    const int H4 = H >> 2;

    float ps = 0.0f, pd = 0.0f, pn = 0.0f;
    for (int i = lane16; i < H4; i += 16) {
        float4 hv = h4[i];
        float4 a = ws4[i], b = wd4[i], c = wn4[i];
        ps = fmaf(hv.x, a.x, fmaf(hv.y, a.y, fmaf(hv.z, a.z, fmaf(hv.w, a.w, ps))));
        pd = fmaf(hv.x, b.x, fmaf(hv.y, b.y, fmaf(hv.z, b.z, fmaf(hv.w, b.w, pd))));
        pn = fmaf(hv.x, c.x, fmaf(hv.y, c.y, fmaf(hv.z, c.z, fmaf(hv.w, c.w, pn))));
    }
    #pragma unroll
    for (int off = 8; off > 0; off >>= 1) {
        ps += __shfl_xor(ps, off, 64);
        pd += __shfl_xor(pd, off, 64);
        pn += __shfl_xor(pn, off, 64);
    }
    if (lane16 == 0) {
        float self = pn + b_node[0];
        s_src[n]   = ps;
        t_dst[n]   = pd + b_edge[0];
        self_sc[n] = self;
        acc[n]     = self;
    }
}

// ---------------- K2: LDS-histogram edge binning ---------------------------
__global__ __launch_bounds__(1024) void edge_bin_kernel(
    const int* __restrict__ ei,          // [2*E]: src row then dst row
    const float* __restrict__ s_src,
    const float* __restrict__ t_dst,
    float* __restrict__ partials,        // [B*N]
    int N, int E, int chunk, int vec_ok)
{
    __shared__ float hist[RANGE_SIZE];
    const int b  = blockIdx.x;
    const int r  = blockIdx.y;
    const int lo = r << RANGE_BITS;
    const int hi = min(lo + RANGE_SIZE, N);

    for (int i = threadIdx.x; i < RANGE_SIZE; i += blockDim.x) hist[i] = 0.0f;
    __syncthreads();

    const int e0 = b * chunk;
    const int e1 = min(e0 + chunk, E);
    if (e0 < e1) {
        if (vec_ok) {
            const int nvec = (e1 - e0) >> 2;
            const int4* __restrict__ dst4 = (const int4*)(ei + E + e0);
            for (int i = threadIdx.x; i < nvec; i += blockDim.x) {
                int4 d = dst4[i];
                const int eb = e0 + 4 * i;
                // src loaded only when dst is in range (saves 3/4 of src traffic)
                if (d.x >= lo && d.x < hi) atomicAdd(&hist[d.x - lo], s_src[ei[eb + 0]] + t_dst[d.x]);
                if (d.y >= lo && d.y < hi) atomicAdd(&hist[d.y - lo], s_src[ei[eb + 1]] + t_dst[d.y]);
                if (d.z >= lo && d.z < hi) atomicAdd(&hist[d.z - lo], s_src[ei[eb + 2]] + t_dst[d.z]);
                if (d.w >= lo && d.w < hi) atomicAdd(&hist[d.w - lo], s_src[ei[eb + 3]] + t_dst[d.w]);
            }
            for (int e = e0 + 4 * nvec + threadIdx.x; e < e1; e += blockDim.x) {
                int d = ei[E + e];
                if (d >= lo && d < hi) atomicAdd(&hist[d - lo], s_src[ei[e]] + t_dst[d]);
            }
        } else {
            for (int e = e0 + threadIdx.x; e < e1; e += blockDim.x) {
                int d = ei[E + e];
                if (d >= lo && d < hi) atomicAdd(&hist[d - lo], s_src[ei[e]] + t_dst[d]);
            }
        }
    }
    __syncthreads();

    float* __restrict__ outp = partials + (size_t)b * N + lo;
    const int len = hi - lo;
    if (((len & 3) == 0)) {
        const int len4 = len >> 2;
        const float4* __restrict__ h4 = (const float4*)hist;
        float4* __restrict__ o4 = (float4*)outp;
        for (int i = threadIdx.x; i < len4; i += blockDim.x) o4[i] = h4[i];
    } else {
        for (int i = threadIdx.x; i < len; i += blockDim.x) outp[i] = hist[i];
    }
}

// Fallback edge path (tiny workspace): agent-scope atomics into acc.
__global__ __launch_bounds__(256) void edge_accum_fallback_kernel(
    const int* __restrict__ ei,
    const float* __restrict__ s_src,
    const float* __restrict__ t_dst,
    float* __restrict__ acc,
    int E)
{
    int e = blockIdx.x * blockDim.x + threadIdx.x;
    if (e >= E) return;
    int s = ei[e];
    int d = ei[E + e];
    atomicAdd(&acc[d], s_src[s] + t_dst[d]);
}

// ---------------- block reduction helpers ----------------------------------
__device__ __forceinline__ float blockReduceMaxB(float v) {
    __shared__ float sm[16];
    #pragma unroll
    for (int off = 32; off > 0; off >>= 1) v = fmaxf(v, __shfl_xor(v, off, 64));
    const int w = threadIdx.x >> 6, l = threadIdx.x & 63;
    const int nw = blockDim.x >> 6;
    if (l == 0) sm[w] = v;
    __syncthreads();
    float r = sm[0];
    for (int i = 1; i < nw; ++i) r = fmaxf(r, sm[i]);
    __syncthreads();
    return r;
}

__device__ __forceinline__ float blockReduceSumB(float v) {
    __shared__ float sm[16];
    #pragma unroll
    for (int off = 32; off > 0; off >>= 1) v += __shfl_xor(v, off, 64);
    const int w = threadIdx.x >> 6, l = threadIdx.x & 63;
    const int nw = blockDim.x >> 6;
    if (l == 0) sm[w] = v;
    __syncthreads();
    float r = 0.0f;
    for (int i = 0; i < nw; ++i) r += sm[i];
    __syncthreads();
    return r;
}

// ---------------- K3: cooperative finalize ---------------------------------
// acc = self + sum_b partials (or acc as-is), softmax, write out. One launch.
__global__ __launch_bounds__(COOP_THREADS) void finalize_coop_kernel(
    const float* __restrict__ self_sc,
    const float* __restrict__ partials,
    const float* __restrict__ acc,
    float* __restrict__ out,
    float* __restrict__ red,             // [2*COOP_BLOCKS]
    int N, int B, int use_partials)
{
    cg::grid_group grid = cg::this_grid();
    const int gid   = blockIdx.x * blockDim.x + threadIdx.x;
    const int gsize = gridDim.x * blockDim.x;

    float vals[MAXITEMS];
    float m = -INFINITY;
    #pragma unroll
    for (int k = 0; k < MAXITEMS; ++k) {
        const int i = gid + k * gsize;
        if (i < N) {
            float v;
            if (use_partials) {
                float v0 = self_sc[i], v1 = 0.0f, v2 = 0.0f, v3 = 0.0f;
                int b = 0;
                for (; b + 4 <= B; b += 4) {
                    v0 += partials[(size_t)(b + 0) * N + i];
                    v1 += partials[(size_t)(b + 1) * N + i];
                    v2 += partials[(size_t)(b + 2) * N + i];
                    v3 += partials[(size_t)(b + 3) * N + i];
                }
                for (; b < B; ++b) v0 += partials[(size_t)b * N + i];
                v = (v0 + v1) + (v2 + v3);
            } else {
                v = acc[i];
            }
            vals[k] = v;
            m = fmaxf(m, v);
        } else {
            vals[k] = -INFINITY;
        }
    }

    m = blockReduceMaxB(m);
    if (threadIdx.x == 0) red[blockIdx.x] = m;
    grid.sync();

    float t = (threadIdx.x < gridDim.x) ? red[threadIdx.x] : -INFINITY;
    const float gmaxv = blockReduceMaxB(t);

    float s = 0.0f;
    #pragma unroll
    for (int k = 0; k < MAXITEMS; ++k) {
        const int i = gid + k * gsize;
        if (i < N) {
            float e = __expf(vals[k] - gmaxv);
            vals[k] = e;
            s += e;
        }
    }
    s = blockReduceSumB(s);
    if (threadIdx.x == 0) red[gridDim.x + blockIdx.x] = s;
    grid.sync();

    float ts = (threadIdx.x < gridDim.x) ? red[gridDim.x + threadIdx.x] : 0.0f;
    const float gsumv = blockReduceSumB(ts);
    const float inv = 1.0f / gsumv;
    #pragma unroll
    for (int k = 0; k < MAXITEMS; ++k) {
        const int i = gid + k * gsize;
        if (i < N) out[i] = vals[k] * inv;
    }
}

// ---------------- non-cooperative fallback tail ----------------------------
__global__ __launch_bounds__(256) void combine_max_kernel(
    const float* __restrict__ self_sc,
    const float* __restrict__ partials,
    float* __restrict__ acc,
    float* __restrict__ gmax,
    int N, int B, int use_partials)
{
    float m = -INFINITY;
    for (int i = blockIdx.x * blockDim.x + threadIdx.x; i < N;
         i += gridDim.x * blockDim.x) {
        float v;
        if (use_partials) {
            float v0 = self_sc[i], v1 = 0.0f, v2 = 0.0f, v3 = 0.0f;
            int b = 0;
            for (; b + 4 <= B; b += 4) {
                v0 += partials[(size_t)(b + 0) * N + i];
                v1 += partials[(size_t)(b + 1) * N + i];
                v2 += partials[(size_t)(b + 2) * N + i];
                v3 += partials[(size_t)(b + 3) * N + i];
            }
            for (; b < B; ++b) v0 += partials[(size_t)b * N + i];
            v = (v0 + v1) + (v2 + v3);
            acc[i] = v;
        } else {
            v = acc[i];
        }
        m = fmaxf(m, v);
    }
    m = blockReduceMaxB(m);
    if (threadIdx.x == 0) atomicMaxFloat(gmax, m);
}

__global__ __launch_bounds__(256) void exp_sum_kernel(
    const float* __restrict__ acc, const float* __restrict__ gmax,
    float* __restrict__ out, float* __restrict__ gsum, int N)
{
    const float mx = *gmax;
    float s = 0.0f;
    for (int i = blockIdx.x * blockDim.x + threadIdx.x; i < N;
         i += gridDim.x * blockDim.x) {
        float v = __expf(acc[i] - mx);
        out[i] = v;
        s += v;
    }
    s = blockReduceSumB(s);
    if (threadIdx.x == 0) atomicAdd(gsum, s);
}

__global__ __launch_bounds__(256) void normalize_kernel(
    float* __restrict__ out, const float* __restrict__ gsum, int N)
{
    int i = blockIdx.x * blockDim.x + threadIdx.x;
    if (i >= N) return;
    out[i] *= (1.0f / *gsum);
}

// ---------------------------------------------------------------------------
extern "C" void kernel_launch(void* const* d_in, const int* in_sizes, int n_in,
                              void* d_out, int out_size, void* d_ws, size_t ws_size,
                              hipStream_t stream) {
    const float* h      = (const float*)d_in[0];
    const int*   ei     = (const int*)  d_in[1];
    const float* W_edge = (const float*)d_in[2];
    const float* b_edge = (const float*)d_in[3];
    const float* W_node = (const float*)d_in[4];
    const float* b_node = (const float*)d_in[5];

    const int H = in_sizes[2] / 2;            // W_edge has 2H elements
    const int N = in_sizes[0] / H;
    const int E = in_sizes[1] / 2;

    float* out     = (float*)d_out;
    float* ws      = (float*)d_ws;
    float* s_src   = ws;
    float* t_dst   = ws + (size_t)N;
    float* self_s  = ws + 2 * (size_t)N;
    float* acc     = ws + 3 * (size_t)N;
    float* gmax    = ws + 4 * (size_t)N;
    float* gsum    = ws + 4 * (size_t)N + 1;
    float* red     = ws + 4 * (size_t)N + 2;
    float* partials = red + 2 * COOP_BLOCKS;

    // Partial copies that fit
    const size_t base_floats = 4 * (size_t)N + 2 + 2 * COOP_BLOCKS;
    int B = 0;
    if (ws_size / sizeof(float) > base_floats) {
        size_t avail = ws_size / sizeof(float) - base_floats;
        B = (int)(avail / (size_t)N);
    }
    if (B > NCHUNKS) B = NCHUNKS;
    const int R = (N + RANGE_SIZE - 1) >> RANGE_BITS;
    const int use_partials = (B >= 16) ? 1 : 0;

    // Cooperative-launch support? (host-side query; no stream ops)
    int dev = 0, coop = 0;
    hipGetDevice(&dev);
    hipDeviceGetAttribute(&coop, hipDeviceAttributeCooperativeLaunch, dev);
    const int use_coop =
        (coop && (size_t)N <= (size_t)COOP_BLOCKS * COOP_THREADS * MAXITEMS) ? 1 : 0;

    // 1) node scores
    {
        int threads = N * 16;
        int grid = (threads + 255) / 256;
        node_scores_kernel<<<grid, 256, 0, stream>>>(
            h, W_edge, b_edge, W_node, b_node,
            s_src, t_dst, self_s, acc, gmax, gsum, N, H);
    }
    // 2) edge accumulation
    if (use_partials) {
        int chunk = (((E + B - 1) / B) + 3) & ~3;   // 4-aligned chunk starts
        int vec_ok = ((E & 3) == 0) ? 1 : 0;
        dim3 grid(B, R);
        edge_bin_kernel<<<grid, 1024, 0, stream>>>(
            ei, s_src, t_dst, partials, N, E, chunk, vec_ok);
    } else {
        int grid = (E + 255) / 256;
        edge_accum_fallback_kernel<<<grid, 256, 0, stream>>>(ei, s_src, t_dst, acc, E);
    }
    // 3) finalize
    if (use_coop) {
        void* args[] = { (void*)&self_s, (void*)&partials, (void*)&acc,
                         (void*)&out, (void*)&red, (void*)&N, (void*)&B,
                         (void*)&use_partials };
        hipLaunchCooperativeKernel((void*)finalize_coop_kernel,
                                   dim3(COOP_BLOCKS), dim3(COOP_THREADS),
                                   args, 0, stream);
    } else {
        combine_max_kernel<<<256, 256, 0, stream>>>(
            self_s, partials, acc, gmax, N, B, use_partials);
        int grid = (N + 255) / 256;
        exp_sum_kernel<<<grid, 256, 0, stream>>>(acc, gmax, out, gsum, N);
        normalize_kernel<<<grid, 256, 0, stream>>>(out, gsum, N);
    }
}

// Round 5
// 120.851 us; speedup vs baseline: 1.5422x; 1.5422x over previous
//
#include <hip/hip_runtime.h>
#include <math.h>

// ---------------------------------------------------------------------------
// RootCauseAttention: per-node scores -> edge segment-sum -> global softmax
//
// Structure (round 5):
//  K1 node_scores: s_src, t_dst(=s_dst+b_edge), self(=s_node+b_node); 16
//     lanes/node, float4 loads.
//  K2 edge_bin: LDS histograms, NO global atomics (rounds 1-2 measured
//     global fp32 atomics at ~18 G/s memory-side RMW regardless of scope).
//     Grid (B=64 chunks) x (R=4 ranges of 16384), 1024 thr/block, 64 KB LDS
//     (2 blocks/CU = 32 waves/CU). dst row loaded int4; src loaded scalar
//     ONLY under the range predicate. Histogram -> partials[b] float4 stores.
//  K3-K5 tail: combine+max, exp+sum, normalize. Plain kernels — round 4
//     showed cooperative grid.sync() spins ~59 us on this 8-XCD chip
//     (system-scope flag spin at the coherent point); 3 launches are cheaper.
//
// Workspace (floats): s_src[N] | t_dst[N] | self[N] | acc[N] | gmax | gsum |
//                     partials[B*N]
// ---------------------------------------------------------------------------

#define RANGE_BITS 14
#define RANGE_SIZE (1 << RANGE_BITS)   // 16384 nodes/range, 64 KB LDS
#define NCHUNKS 64

__device__ __forceinline__ void atomicMaxFloat(float* addr, float val) {
    if (val >= 0.0f) atomicMax((int*)addr, __float_as_int(val));
    else             atomicMin((unsigned int*)addr, __float_as_uint(val));
}

// ---------------- K1: node scores (16 lanes/node, float4) ------------------
__global__ __launch_bounds__(256) void node_scores_kernel(
    const float* __restrict__ h,
    const float* __restrict__ W_edge,   // [2H]
    const float* __restrict__ b_edge,   // [1]
    const float* __restrict__ W_node,   // [H]
    const float* __restrict__ b_node,   // [1]
    float* __restrict__ s_src,
    float* __restrict__ t_dst,
    float* __restrict__ self_sc,
    float* __restrict__ acc,            // pre-init to self (fallback path)
    float* __restrict__ gmax,
    float* __restrict__ gsum,
    int N, int H)
{
    if (blockIdx.x == 0 && threadIdx.x == 0) { *gmax = -INFINITY; *gsum = 0.0f; }

    const int lane16 = threadIdx.x & 15;
    const int n = (blockIdx.x * blockDim.x + threadIdx.x) >> 4;
    if (n >= N) return;

    const float4* __restrict__ h4  = (const float4*)(h + (size_t)n * H);
    const float4* __restrict__ ws4 = (const float4*)(W_edge);
    const float4* __restrict__ wd4 = (const float4*)(W_edge + H);
    const float4* __restrict__ wn4 = (const float4*)(W_node);
    const int H4 = H >> 2;

    float ps = 0.0f, pd = 0.0f, pn = 0.0f;
    for (int i = lane16; i < H4; i += 16) {
        float4 hv = h4[i];
        float4 a = ws4[i], b = wd4[i], c = wn4[i];
        ps = fmaf(hv.x, a.x, fmaf(hv.y, a.y, fmaf(hv.z, a.z, fmaf(hv.w, a.w, ps))));
        pd = fmaf(hv.x, b.x, fmaf(hv.y, b.y, fmaf(hv.z, b.z, fmaf(hv.w, b.w, pd))));
        pn = fmaf(hv.x, c.x, fmaf(hv.y, c.y, fmaf(hv.z, c.z, fmaf(hv.w, c.w, pn))));
    }
    #pragma unroll
    for (int off = 8; off > 0; off >>= 1) {
        ps += __shfl_xor(ps, off, 64);
        pd += __shfl_xor(pd, off, 64);
        pn += __shfl_xor(pn, off, 64);
    }
    if (lane16 == 0) {
        float self = pn + b_node[0];
        s_src[n]   = ps;
        t_dst[n]   = pd + b_edge[0];
        self_sc[n] = self;
        acc[n]     = self;
    }
}

// ---------------- K2: LDS-histogram edge binning ---------------------------
__global__ __launch_bounds__(1024) void edge_bin_kernel(
    const int* __restrict__ ei,          // [2*E]: src row then dst row
    const float* __restrict__ s_src,
    const float* __restrict__ t_dst,
    float* __restrict__ partials,        // [B*N]
    int N, int E, int chunk, int vec_ok)
{
    __shared__ float hist[RANGE_SIZE];
    const int b  = blockIdx.x;
    const int r  = blockIdx.y;
    const int lo = r << RANGE_BITS;
    const int hi = min(lo + RANGE_SIZE, N);

    for (int i = threadIdx.x; i < RANGE_SIZE; i += blockDim.x) hist[i] = 0.0f;
    __syncthreads();

    const int e0 = b * chunk;
    const int e1 = min(e0 + chunk, E);
    if (e0 < e1) {
        if (vec_ok) {
            const int nvec = (e1 - e0) >> 2;
            const int4* __restrict__ dst4 = (const int4*)(ei + E + e0);
            for (int i = threadIdx.x; i < nvec; i += blockDim.x) {
                int4 d = dst4[i];
                const int eb = e0 + 4 * i;
                // src loaded only when dst in range (3/4 of src traffic saved)
                if (d.x >= lo && d.x < hi) atomicAdd(&hist[d.x - lo], s_src[ei[eb + 0]] + t_dst[d.x]);
                if (d.y >= lo && d.y < hi) atomicAdd(&hist[d.y - lo], s_src[ei[eb + 1]] + t_dst[d.y]);
                if (d.z >= lo && d.z < hi) atomicAdd(&hist[d.z - lo], s_src[ei[eb + 2]] + t_dst[d.z]);
                if (d.w >= lo && d.w < hi) atomicAdd(&hist[d.w - lo], s_src[ei[eb + 3]] + t_dst[d.w]);
            }
            for (int e = e0 + 4 * nvec + threadIdx.x; e < e1; e += blockDim.x) {
                int d = ei[E + e];
                if (d >= lo && d < hi) atomicAdd(&hist[d - lo], s_src[ei[e]] + t_dst[d]);
            }
        } else {
            for (int e = e0 + threadIdx.x; e < e1; e += blockDim.x) {
                int d = ei[E + e];
                if (d >= lo && d < hi) atomicAdd(&hist[d - lo], s_src[ei[e]] + t_dst[d]);
            }
        }
    }
    __syncthreads();

    float* __restrict__ outp = partials + (size_t)b * N + lo;
    const int len = hi - lo;
    if ((len & 3) == 0) {
        const int len4 = len >> 2;
        const float4* __restrict__ h4 = (const float4*)hist;
        float4* __restrict__ o4 = (float4*)outp;
        for (int i = threadIdx.x; i < len4; i += blockDim.x) o4[i] = h4[i];
    } else {
        for (int i = threadIdx.x; i < len; i += blockDim.x) outp[i] = hist[i];
    }
}

// Fallback edge path (tiny workspace): agent-scope atomics into acc.
__global__ __launch_bounds__(256) void edge_accum_fallback_kernel(
    const int* __restrict__ ei,
    const float* __restrict__ s_src,
    const float* __restrict__ t_dst,
    float* __restrict__ acc,
    int E)
{
    int e = blockIdx.x * blockDim.x + threadIdx.x;
    if (e >= E) return;
    int s = ei[e];
    int d = ei[E + e];
    atomicAdd(&acc[d], s_src[s] + t_dst[d]);
}

// ---------------- block reduction helpers ----------------------------------
__device__ __forceinline__ float blockReduceMaxB(float v) {
    __shared__ float sm[16];
    #pragma unroll
    for (int off = 32; off > 0; off >>= 1) v = fmaxf(v, __shfl_xor(v, off, 64));
    const int w = threadIdx.x >> 6, l = threadIdx.x & 63;
    const int nw = blockDim.x >> 6;
    if (l == 0) sm[w] = v;
    __syncthreads();
    float r = sm[0];
    for (int i = 1; i < nw; ++i) r = fmaxf(r, sm[i]);
    __syncthreads();
    return r;
}

__device__ __forceinline__ float blockReduceSumB(float v) {
    __shared__ float sm[16];
    #pragma unroll
    for (int off = 32; off > 0; off >>= 1) v += __shfl_xor(v, off, 64);
    const int w = threadIdx.x >> 6, l = threadIdx.x & 63;
    const int nw = blockDim.x >> 6;
    if (l == 0) sm[w] = v;
    __syncthreads();
    float r = 0.0f;
    for (int i = 0; i < nw; ++i) r += sm[i];
    __syncthreads();
    return r;
}

// ---------------- K3: combine partials + self, global max ------------------
__global__ __launch_bounds__(256) void combine_max_kernel(
    const float* __restrict__ self_sc,
    const float* __restrict__ partials,
    float* __restrict__ acc,
    float* __restrict__ gmax,
    int N, int B, int use_partials)
{
    float m = -INFINITY;
    for (int i = blockIdx.x * blockDim.x + threadIdx.x; i < N;
         i += gridDim.x * blockDim.x) {
        float v;
        if (use_partials) {
            float v0 = self_sc[i], v1 = 0.0f, v2 = 0.0f, v3 = 0.0f;
            int b = 0;
            for (; b + 4 <= B; b += 4) {
                v0 += partials[(size_t)(b + 0) * N + i];
                v1 += partials[(size_t)(b + 1) * N + i];
                v2 += partials[(size_t)(b + 2) * N + i];
                v3 += partials[(size_t)(b + 3) * N + i];
            }
            for (; b < B; ++b) v0 += partials[(size_t)b * N + i];
            v = (v0 + v1) + (v2 + v3);
            acc[i] = v;
        } else {
            v = acc[i];
        }
        m = fmaxf(m, v);
    }
    m = blockReduceMaxB(m);
    if (threadIdx.x == 0) atomicMaxFloat(gmax, m);
}

// ---------------- K4: exp + partial sum ------------------------------------
__global__ __launch_bounds__(256) void exp_sum_kernel(
    const float* __restrict__ acc, const float* __restrict__ gmax,
    float* __restrict__ out, float* __restrict__ gsum, int N)
{
    const float mx = *gmax;
    float s = 0.0f;
    for (int i = blockIdx.x * blockDim.x + threadIdx.x; i < N;
         i += gridDim.x * blockDim.x) {
        float v = __expf(acc[i] - mx);
        out[i] = v;
        s += v;
    }
    s = blockReduceSumB(s);
    if (threadIdx.x == 0) atomicAdd(gsum, s);
}

// ---------------- K5: normalize --------------------------------------------
__global__ __launch_bounds__(256) void normalize_kernel(
    float* __restrict__ out, const float* __restrict__ gsum, int N)
{
    int i = blockIdx.x * blockDim.x + threadIdx.x;
    if (i >= N) return;
    out[i] *= (1.0f / *gsum);
}

// ---------------------------------------------------------------------------
extern "C" void kernel_launch(void* const* d_in, const int* in_sizes, int n_in,
                              void* d_out, int out_size, void* d_ws, size_t ws_size,
                              hipStream_t stream) {
    const float* h      = (const float*)d_in[0];
    const int*   ei     = (const int*)  d_in[1];
    const float* W_edge = (const float*)d_in[2];
    const float* b_edge = (const float*)d_in[3];
    const float* W_node = (const float*)d_in[4];
    const float* b_node = (const float*)d_in[5];

    const int H = in_sizes[2] / 2;            // W_edge has 2H elements
    const int N = in_sizes[0] / H;
    const int E = in_sizes[1] / 2;

    float* out      = (float*)d_out;
    float* ws       = (float*)d_ws;
    float* s_src    = ws;
    float* t_dst    = ws + (size_t)N;
    float* self_s   = ws + 2 * (size_t)N;
    float* acc      = ws + 3 * (size_t)N;
    float* gmax     = ws + 4 * (size_t)N;
    float* gsum     = ws + 4 * (size_t)N + 1;
    float* partials = ws + 4 * (size_t)N + 2;

    // Partial copies that fit
    const size_t base_floats = 4 * (size_t)N + 2;
    int B = 0;
    if (ws_size / sizeof(float) > base_floats) {
        size_t avail = ws_size / sizeof(float) - base_floats;
        B = (int)(avail / (size_t)N);
    }
    if (B > NCHUNKS) B = NCHUNKS;
    const int R = (N + RANGE_SIZE - 1) >> RANGE_BITS;
    const int use_partials = (B >= 16) ? 1 : 0;

    // 1) node scores
    {
        int threads = N * 16;
        int grid = (threads + 255) / 256;
        node_scores_kernel<<<grid, 256, 0, stream>>>(
            h, W_edge, b_edge, W_node, b_node,
            s_src, t_dst, self_s, acc, gmax, gsum, N, H);
    }
    // 2) edge accumulation
    if (use_partials) {
        int chunk = (((E + B - 1) / B) + 3) & ~3;   // 4-aligned chunk starts
        int vec_ok = ((E & 3) == 0) ? 1 : 0;
        dim3 grid(B, R);
        edge_bin_kernel<<<grid, 1024, 0, stream>>>(
            ei, s_src, t_dst, partials, N, E, chunk, vec_ok);
    } else {
        int grid = (E + 255) / 256;
        edge_accum_fallback_kernel<<<grid, 256, 0, stream>>>(ei, s_src, t_dst, acc, E);
    }
    // 3-5) combine+max, exp+sum, normalize
    combine_max_kernel<<<256, 256, 0, stream>>>(
        self_s, partials, acc, gmax, N, B, use_partials);
    {
        int grid = (N + 255) / 256;
        exp_sum_kernel<<<grid, 256, 0, stream>>>(acc, gmax, out, gsum, N);
        normalize_kernel<<<grid, 256, 0, stream>>>(out, gsum, N);
    }
}

// Round 6
// 115.498 us; speedup vs baseline: 1.6136x; 1.0463x over previous
//
#include <hip/hip_runtime.h>
#include <math.h>

// ---------------------------------------------------------------------------
// RootCauseAttention: per-node scores -> edge segment-sum -> global softmax
//
// Structure (round 6):
//  K1 node_scores: s_src, t_dst(=s_dst+b_edge), self(=s_node+b_node); 16
//     lanes/node, float4 loads.
//  K2 edge_bin: LDS histograms, NO global atomics (rounds 1-2: global fp32
//     atomics run ~18 G/s memory-side RMW regardless of scope). Grid
//     (B=64 chunks) x (R=4 ranges of 16384), 1024 thr/block, 64 KB LDS.
//     dst row int4; src loaded scalar ONLY under the range predicate.
//  K3 combine_stats: acc = self + sum_b partials; ONLINE softmax stats
//     (m,l) per block -> red[256|256]. No atomics (round-4 showed grid.sync
//     spins ~59 us; rounds 1-2 showed scalar atomics serialize memory-side).
//  K4 finalize: each block redundantly reduces the 256 (m,l) pairs (2 KB,
//     L2-hot) -> (M,L), writes out = exp(acc-M)/L. 4 kernels total.
//
// Workspace (floats): s_src[N] | t_dst[N] | self[N] | acc[N] | red[512] |
//                     partials[B*N]
// ---------------------------------------------------------------------------

#define RANGE_BITS 14
#define RANGE_SIZE (1 << RANGE_BITS)   // 16384 nodes/range, 64 KB LDS
#define NCHUNKS 64
#define STAT_BLOCKS 256                // K3 grid size (fixed; red[] sizing)

// ---------------- K1: node scores (16 lanes/node, float4) ------------------
__global__ __launch_bounds__(256) void node_scores_kernel(
    const float* __restrict__ h,
    const float* __restrict__ W_edge,   // [2H]
    const float* __restrict__ b_edge,   // [1]
    const float* __restrict__ W_node,   // [H]
    const float* __restrict__ b_node,   // [1]
    float* __restrict__ s_src,
    float* __restrict__ t_dst,
    float* __restrict__ self_sc,
    float* __restrict__ acc,            // pre-init to self (fallback path)
    int N, int H)
{
    const int lane16 = threadIdx.x & 15;
    const int n = (blockIdx.x * blockDim.x + threadIdx.x) >> 4;
    if (n >= N) return;

    const float4* __restrict__ h4  = (const float4*)(h + (size_t)n * H);
    const float4* __restrict__ ws4 = (const float4*)(W_edge);
    const float4* __restrict__ wd4 = (const float4*)(W_edge + H);
    const float4* __restrict__ wn4 = (const float4*)(W_node);
    const int H4 = H >> 2;

    float ps = 0.0f, pd = 0.0f, pn = 0.0f;
    for (int i = lane16; i < H4; i += 16) {
        float4 hv = h4[i];
        float4 a = ws4[i], b = wd4[i], c = wn4[i];
        ps = fmaf(hv.x, a.x, fmaf(hv.y, a.y, fmaf(hv.z, a.z, fmaf(hv.w, a.w, ps))));
        pd = fmaf(hv.x, b.x, fmaf(hv.y, b.y, fmaf(hv.z, b.z, fmaf(hv.w, b.w, pd))));
        pn = fmaf(hv.x, c.x, fmaf(hv.y, c.y, fmaf(hv.z, c.z, fmaf(hv.w, c.w, pn))));
    }
    #pragma unroll
    for (int off = 8; off > 0; off >>= 1) {
        ps += __shfl_xor(ps, off, 64);
        pd += __shfl_xor(pd, off, 64);
        pn += __shfl_xor(pn, off, 64);
    }
    if (lane16 == 0) {
        float self = pn + b_node[0];
        s_src[n]   = ps;
        t_dst[n]   = pd + b_edge[0];
        self_sc[n] = self;
        acc[n]     = self;
    }
}

// ---------------- K2: LDS-histogram edge binning ---------------------------
__global__ __launch_bounds__(1024) void edge_bin_kernel(
    const int* __restrict__ ei,          // [2*E]: src row then dst row
    const float* __restrict__ s_src,
    const float* __restrict__ t_dst,
    float* __restrict__ partials,        // [B*N]
    int N, int E, int chunk, int vec_ok)
{
    __shared__ float hist[RANGE_SIZE];
    const int b  = blockIdx.x;
    const int r  = blockIdx.y;
    const int lo = r << RANGE_BITS;
    const int hi = min(lo + RANGE_SIZE, N);
    const unsigned span = (unsigned)(hi - lo);

    for (int i = threadIdx.x; i < RANGE_SIZE; i += blockDim.x) hist[i] = 0.0f;
    __syncthreads();

    const int e0 = b * chunk;
    const int e1 = min(e0 + chunk, E);
    if (e0 < e1) {
        if (vec_ok) {
            const int nvec = (e1 - e0) >> 2;
            const int4* __restrict__ dst4 = (const int4*)(ei + E + e0);
            for (int i = threadIdx.x; i < nvec; i += blockDim.x) {
                int4 d = dst4[i];
                const int eb = e0 + 4 * i;
                unsigned ux = (unsigned)(d.x - lo), uy = (unsigned)(d.y - lo);
                unsigned uz = (unsigned)(d.z - lo), uw = (unsigned)(d.w - lo);
                // src loaded only when dst in range (3/4 of src traffic saved)
                if (ux < span) atomicAdd(&hist[ux], s_src[ei[eb + 0]] + t_dst[d.x]);
                if (uy < span) atomicAdd(&hist[uy], s_src[ei[eb + 1]] + t_dst[d.y]);
                if (uz < span) atomicAdd(&hist[uz], s_src[ei[eb + 2]] + t_dst[d.z]);
                if (uw < span) atomicAdd(&hist[uw], s_src[ei[eb + 3]] + t_dst[d.w]);
            }
            for (int e = e0 + 4 * nvec + threadIdx.x; e < e1; e += blockDim.x) {
                int d = ei[E + e];
                unsigned u = (unsigned)(d - lo);
                if (u < span) atomicAdd(&hist[u], s_src[ei[e]] + t_dst[d]);
            }
        } else {
            for (int e = e0 + threadIdx.x; e < e1; e += blockDim.x) {
                int d = ei[E + e];
                unsigned u = (unsigned)(d - lo);
                if (u < span) atomicAdd(&hist[u], s_src[ei[e]] + t_dst[d]);
            }
        }
    }
    __syncthreads();

    float* __restrict__ outp = partials + (size_t)b * N + lo;
    const int len = hi - lo;
    if ((len & 3) == 0) {
        const int len4 = len >> 2;
        const float4* __restrict__ h4 = (const float4*)hist;
        float4* __restrict__ o4 = (float4*)outp;
        for (int i = threadIdx.x; i < len4; i += blockDim.x) o4[i] = h4[i];
    } else {
        for (int i = threadIdx.x; i < len; i += blockDim.x) outp[i] = hist[i];
    }
}

// Fallback edge path (tiny workspace): agent-scope atomics into acc.
__global__ __launch_bounds__(256) void edge_accum_fallback_kernel(
    const int* __restrict__ ei,
    const float* __restrict__ s_src,
    const float* __restrict__ t_dst,
    float* __restrict__ acc,
    int E)
{
    int e = blockIdx.x * blockDim.x + threadIdx.x;
    if (e >= E) return;
    int s = ei[e];
    int d = ei[E + e];
    atomicAdd(&acc[d], s_src[s] + t_dst[d]);
}

// ---------------- block reduction helpers ----------------------------------
__device__ __forceinline__ float blockReduceMaxB(float v) {
    __shared__ float sm[16];
    #pragma unroll
    for (int off = 32; off > 0; off >>= 1) v = fmaxf(v, __shfl_xor(v, off, 64));
    const int w = threadIdx.x >> 6, l = threadIdx.x & 63;
    const int nw = blockDim.x >> 6;
    if (l == 0) sm[w] = v;
    __syncthreads();
    float r = sm[0];
    for (int i = 1; i < nw; ++i) r = fmaxf(r, sm[i]);
    __syncthreads();
    return r;
}

__device__ __forceinline__ float blockReduceSumB(float v) {
    __shared__ float sm[16];
    #pragma unroll
    for (int off = 32; off > 0; off >>= 1) v += __shfl_xor(v, off, 64);
    const int w = threadIdx.x >> 6, l = threadIdx.x & 63;
    const int nw = blockDim.x >> 6;
    if (l == 0) sm[w] = v;
    __syncthreads();
    float r = 0.0f;
    for (int i = 0; i < nw; ++i) r += sm[i];
    __syncthreads();
    return r;
}

// ---------------- K3: combine + online softmax stats -----------------------
// Grid MUST be STAT_BLOCKS blocks. red[b] = m_b, red[STAT_BLOCKS+b] = l_b.
__global__ __launch_bounds__(256) void combine_stats_kernel(
    const float* __restrict__ self_sc,
    const float* __restrict__ partials,
    float* __restrict__ acc,
    float* __restrict__ red,
    int N, int B, int use_partials)
{
    float m = -INFINITY, l = 0.0f;
    for (int i = blockIdx.x * blockDim.x + threadIdx.x; i < N;
         i += gridDim.x * blockDim.x) {
        float v;
        if (use_partials) {
            float v0 = self_sc[i], v1 = 0.0f, v2 = 0.0f, v3 = 0.0f;
            int b = 0;
            for (; b + 4 <= B; b += 4) {
                v0 += partials[(size_t)(b + 0) * N + i];
                v1 += partials[(size_t)(b + 1) * N + i];
                v2 += partials[(size_t)(b + 2) * N + i];
                v3 += partials[(size_t)(b + 3) * N + i];
            }
            for (; b < B; ++b) v0 += partials[(size_t)b * N + i];
            v = (v0 + v1) + (v2 + v3);
            acc[i] = v;
        } else {
            v = acc[i];
        }
        // online (m, l) update
        float nm = fmaxf(m, v);
        l = l * __expf(m - nm) + __expf(v - nm);
        m = nm;
    }
    // block-combine online stats
    float mb = blockReduceMaxB(m);
    float ladj = (m == -INFINITY) ? 0.0f : l * __expf(m - mb);
    float lb = blockReduceSumB(ladj);
    if (threadIdx.x == 0) {
        red[blockIdx.x] = mb;
        red[STAT_BLOCKS + blockIdx.x] = lb;
    }
}

// ---------------- K4: finalize (redundant stat reduce + normalize) ---------
__global__ __launch_bounds__(256) void finalize_kernel(
    const float* __restrict__ acc,
    const float* __restrict__ red,
    float* __restrict__ out,
    int N)
{
    // every block redundantly reduces the 256 (m,l) pairs (2 KB, L2-hot)
    float m = red[threadIdx.x];
    float l = red[STAT_BLOCKS + threadIdx.x];
    float M = blockReduceMaxB(m);
    float L = blockReduceSumB(l * __expf(m - M));
    const float inv = 1.0f / L;

    int i = blockIdx.x * blockDim.x + threadIdx.x;
    if (i < N) out[i] = __expf(acc[i] - M) * inv;
}

// ---------------------------------------------------------------------------
extern "C" void kernel_launch(void* const* d_in, const int* in_sizes, int n_in,
                              void* d_out, int out_size, void* d_ws, size_t ws_size,
                              hipStream_t stream) {
    const float* h      = (const float*)d_in[0];
    const int*   ei     = (const int*)  d_in[1];
    const float* W_edge = (const float*)d_in[2];
    const float* b_edge = (const float*)d_in[3];
    const float* W_node = (const float*)d_in[4];
    const float* b_node = (const float*)d_in[5];

    const int H = in_sizes[2] / 2;            // W_edge has 2H elements
    const int N = in_sizes[0] / H;
    const int E = in_sizes[1] / 2;

    float* out      = (float*)d_out;
    float* ws       = (float*)d_ws;
    float* s_src    = ws;
    float* t_dst    = ws + (size_t)N;
    float* self_s   = ws + 2 * (size_t)N;
    float* acc      = ws + 3 * (size_t)N;
    float* red      = ws + 4 * (size_t)N;
    float* partials = red + 2 * STAT_BLOCKS;

    // Partial copies that fit
    const size_t base_floats = 4 * (size_t)N + 2 * STAT_BLOCKS;
    int B = 0;
    if (ws_size / sizeof(float) > base_floats) {
        size_t avail = ws_size / sizeof(float) - base_floats;
        B = (int)(avail / (size_t)N);
    }
    if (B > NCHUNKS) B = NCHUNKS;
    const int R = (N + RANGE_SIZE - 1) >> RANGE_BITS;
    const int use_partials = (B >= 16) ? 1 : 0;

    // 1) node scores
    {
        int threads = N * 16;
        int grid = (threads + 255) / 256;
        node_scores_kernel<<<grid, 256, 0, stream>>>(
            h, W_edge, b_edge, W_node, b_node,
            s_src, t_dst, self_s, acc, N, H);
    }
    // 2) edge accumulation
    if (use_partials) {
        int chunk = (((E + B - 1) / B) + 3) & ~3;   // 4-aligned chunk starts
        int vec_ok = ((E & 3) == 0) ? 1 : 0;
        dim3 grid(B, R);
        edge_bin_kernel<<<grid, 1024, 0, stream>>>(
            ei, s_src, t_dst, partials, N, E, chunk, vec_ok);
    } else {
        int grid = (E + 255) / 256;
        edge_accum_fallback_kernel<<<grid, 256, 0, stream>>>(ei, s_src, t_dst, acc, E);
    }
    // 3) combine + online softmax stats (fixed 256-block grid)
    combine_stats_kernel<<<STAT_BLOCKS, 256, 0, stream>>>(
        self_s, partials, acc, red, N, B, use_partials);
    // 4) finalize: redundant stat reduce per block + normalize
    {
        int grid = (N + 255) / 256;
        finalize_kernel<<<grid, 256, 0, stream>>>(acc, red, out, N);
    }
}